// Round 3
// baseline (2365.338 us; speedup 1.0000x reference)
//
#include <hip/hip_runtime.h>

#define NROWS 8192
#define RPB   64
#define TPB   1024     // 16 waves/block, 128 blocks, 1 block/CU (LDS-bound)
#define NBLK  128

// workspace layout (float offsets)
#define OFF_W1   0          // 1024
#define OFF_W2   1024       // 1024
#define OFF_WIN  2048       // 102*34 = 3468
#define OFF_WFC2 5516       // 1024
#define OFF_M    6540       // 32*34 = 1088
#define OFF_B12  7628       // 32
#define OFF_BIN  7660       // 102
#define OFF_B2   7762       // 32
#define OFF_BFC2 7794       // 32
#define OFF_LNG  7826       // 32
#define OFF_LNB  7858       // 32
#define OFF_BAR  7904       // 64 ints (per-step grid-barrier counters)
#define OFF_QKV0 8192
#define QKVN     (NROWS*102)          // feature-major: qkv[e][row]
#define OFF_QKV1 (OFF_QKV0 + QKVN)

__global__ __launch_bounds__(256) void setup_kernel(
    const float* __restrict__ W_x2h, const float* __restrict__ b_x2h,
    const float* __restrict__ W_h2h, const float* __restrict__ b_h2h,
    const float* __restrict__ W_fc2, const float* __restrict__ b_fc2,
    const float* __restrict__ ln_g,  const float* __restrict__ ln_b,
    const float* __restrict__ W_fcsa,const float* __restrict__ b_fcsa,
    const float* __restrict__ W_in,  const float* __restrict__ b_in,
    const float* __restrict__ W_out, const float* __restrict__ b_out,
    float* __restrict__ ws)
{
  int t = blockIdx.x*blockDim.x + threadIdx.x;
  int stride = gridDim.x*blockDim.x;
  for (int i=t;i<1024;i+=stride) ws[OFF_W1+i]   = W_x2h[i];
  for (int i=t;i<1024;i+=stride) ws[OFF_W2+i]   = W_h2h[i];
  for (int i=t;i<3468;i+=stride) ws[OFF_WIN+i]  = W_in[i];
  for (int i=t;i<1024;i+=stride) ws[OFF_WFC2+i] = W_fc2[i];
  for (int i=t;i<32;i+=stride)   ws[OFF_B12+i]  = b_x2h[i] + b_h2h[i];
  for (int i=t;i<102;i+=stride)  ws[OFF_BIN+i]  = b_in[i];
  for (int i=t;i<32;i+=stride)   ws[OFF_BFC2+i] = b_fc2[i];
  for (int i=t;i<32;i+=stride)   ws[OFF_LNG+i]  = ln_g[i];
  for (int i=t;i<32;i+=stride)   ws[OFF_LNB+i]  = ln_b[i];
  // zero grid-barrier counters (re-zeroed every launch/graph replay)
  for (int i=t;i<64;i+=stride)   ((int*)(ws+OFF_BAR))[i] = 0;
  // M = W_fcsa (32x34) @ W_out (34x34)
  for (int idx=t; idx<1088; idx+=stride) {
    int j = idx/34, f = idx - j*34;
    float acc = 0.f;
    for (int e=0;e<34;++e)
      acc += W_fcsa[j*34+e] * W_out[e*34+f];
    ws[OFF_M+idx] = acc;
  }
  for (int j=t;j<32;j+=stride){
    float acc = b_fcsa[j];
    for (int e=0;e<34;++e) acc += W_fcsa[j*34+e] * b_out[e];
    ws[OFF_B2+j] = acc;
  }
}

// Persistent kernel: all 60 steps in one REGULAR launch.
// Co-residency is structural: 130 KB static LDS -> 1 block/CU, 128 blocks on a
// 256-CU chip -> all blocks dispatched immediately. Cross-block qkv exchange is
// published by a hand-rolled device-scope barrier (release fence + atomic count
// + acquire fence), one per step -- the same lowering cg::grid.sync() uses,
// without the cooperative-launch API (which broke the harness in R2).
// Block b owns rows [64b,64b+64) (one batch x grid-row stripe) for the whole
// sequence: h_new / h' / pred persist in LDS; phase 0 bulk-stages the 3 needed
// qkv grid-rows so scores/softmax/PV are pure LDS.
__global__ __launch_bounds__(TPB) void fused_kernel(
    float* __restrict__ ws,
    const float* __restrict__ x,
    float* __restrict__ out)
{
  const float* W1f   = ws + OFF_W1;
  const float* W2f   = ws + OFF_W2;
  const float* Winf  = ws + OFF_WIN;
  const float* Wfc2f = ws + OFF_WFC2;
  const float* Mf    = ws + OFF_M;
  const float* b12f  = ws + OFF_B12;
  const float* binf  = ws + OFF_BIN;
  const float* b2f   = ws + OFF_B2;
  const float* bfc2f = ws + OFF_BFC2;
  const float* lngf  = ws + OFF_LNG;
  const float* lnbf  = ws + OFF_LNB;
  int*  bar = (int*)(ws + OFF_BAR);
  float* q0 = ws + OFF_QKV0;
  float* q1 = ws + OFF_QKV1;

  __shared__ float sQKV[3][102][64]; // staged qkv rows (br-1,br,br+1) x feat x gc
  __shared__ float sS[RPB][13];      // 9 scores (stride 13: conflict-free)
  __shared__ float sO[RPB][35];      // attention output (34; stride 35 cf)
  __shared__ float sHp[RPB][33];     // h' (persistent across steps)
  __shared__ float sG[RPB][33];      // pre-LN fc2 output
  __shared__ float sPred[RPB][33];   // pred (next-step input, persistent)
  __shared__ float sHn[RPB][33];     // h_new (tanh output, persistent)
  __shared__ float sX[RPB][33];      // staged x chunk (steps 0..9)

  const int tid = threadIdx.x;
  const int lr  = tid & 63;
  const int wu  = __builtin_amdgcn_readfirstlane(tid >> 6);  // wave id 0..15
  const int base= blockIdx.x * RPB;
  const int r   = base + lr;
  // block covers exactly one (batch, grid-row); gc == lr
  const int bb  = base >> 12;                    // uniform
  const int grb = (base & 4095) >> 6;            // uniform (UNclamped, for pl)
  const int brb = (grb < 1) ? 1 : ((grb > 62) ? 62 : grb);  // uniform clamp
  const int bc  = (lr < 1) ? 1 : ((lr > 62) ? 62 : lr);     // per-lane col clamp
  const int rb0 = (bb << 12) + ((brb - 1) << 6); // global row of stage slot 0

  for (int i = 0; i < 60; ++i) {
    const int stepB = i - 1;
    const int stepA = (i <= 58) ? i : -1;
    const float* qR = ((i + 1) & 1) ? q1 : q0;   // qkv of step i-1
    float*       qW = (i & 1) ? q1 : q0;         // qkv of step i

    // ---- phase 0: bulk-stage qkv rows into LDS (all 16 waves, coalesced) ----
    if (stepB >= 0) {
      #pragma unroll
      for (int k = 0; k < 20; ++k) {
        int chunk = wu + 16*k;                   // wave-uniform
        if (chunk < 306) {
          int drp = chunk / 102;                 // 0..2, SGPR
          int e   = chunk - drp*102;             // 0..101, SGPR
          sQKV[drp][e][lr] = qR[(size_t)e*NROWS + rb0 + (drp<<6) + lr];
        }
      }
    } else {
      // step 0: h' = 0
      sHp[lr][2*wu] = 0.f; sHp[lr][2*wu+1] = 0.f;
    }
    if (stepA >= 0 && stepA < 10) {
      size_t xbase = ((size_t)stepA*NROWS + base)*32;
      #pragma unroll
      for (int it = 0; it < 2; ++it) {
        int idx = tid + it*TPB;
        sX[idx>>5][idx&31] = x[xbase + idx];
      }
    }
    __syncthreads();

    if (stepB >= 0) {
      // ---- phase 1: scores (waves 0..8, m=wu) — pure LDS ----
      if (wu < 9) {
        const int slot = wu / 3;                 // uniform
        const int col  = bc + (wu - slot*3 - 1); // 0..63
        float acc = 0.f;
        #pragma unroll
        for (int e = 0; e < 34; ++e)
          acc += sQKV[1][e][bc] * sQKV[slot][34+e][col];
        sS[lr][wu] = acc * 0.1714985851425088f;  // 1/sqrt(34)
      }
      __syncthreads();
      // ---- phase 2: softmax (redundant per wave) + o slice — pure LDS ----
      {
        float sc[9]; float mx = -1e30f;
        #pragma unroll
        for (int m=0;m<9;++m){ sc[m]=sS[lr][m]; mx=fmaxf(mx,sc[m]); }
        float sum=0.f;
        #pragma unroll
        for (int m=0;m<9;++m){ sc[m]=__expf(sc[m]-mx); sum+=sc[m]; }
        float inv = 1.f/sum;
        float o0=0.f, o1=0.f, o2=0.f;
        const bool e2ok = (wu < 2);              // wave-uniform
        #pragma unroll
        for (int m=0;m<9;++m){
          const int slot = m/3;
          const int col  = bc + (m - slot*3 - 1);
          float wm = sc[m]*inv;
          o0 += wm * sQKV[slot][68+wu][col];
          o1 += wm * sQKV[slot][84+wu][col];
          if (e2ok) o2 += wm * sQKV[slot][100+wu][col];
        }
        sO[lr][wu]    = o0;
        sO[lr][wu+16] = o1;
        if (e2ok) sO[lr][wu+32] = o2;
      }
      __syncthreads();
      // ---- phase 3: h' = h_new(LDS) + o @ M^T + b2 : wave wu -> j=2wu,2wu+1 ----
      {
        const int j0 = wu*2;
        float a0 = b2f[j0], a1 = b2f[j0+1];
        #pragma unroll
        for (int e=0;e<34;++e){
          float ov = sO[lr][e];
          a0 += ov * Mf[j0*34+e];                // s_load weights
          a1 += ov * Mf[(j0+1)*34+e];
        }
        sHp[lr][j0]   = sHn[lr][j0]   + a0;
        sHp[lr][j0+1] = sHn[lr][j0+1] + a1;
      }
      __syncthreads();
      // ---- phase 4: g = h' @ Wfc2^T + b ----
      {
        const int j0 = wu*2;
        float g0 = bfc2f[j0], g1 = bfc2f[j0+1];
        #pragma unroll
        for (int ii=0;ii<32;++ii){
          float hv = sHp[lr][ii];
          g0 += hv * Wfc2f[j0*32+ii];            // s_load
          g1 += hv * Wfc2f[(j0+1)*32+ii];
        }
        sG[lr][j0]=g0; sG[lr][j0+1]=g1;
      }
      __syncthreads();
      // ---- phase 5: layernorm -> sPred ----
      {
        float mu=0.f;
        #pragma unroll
        for (int ii=0;ii<32;++ii) mu += sG[lr][ii];
        mu *= 0.03125f;
        float var=0.f;
        #pragma unroll
        for (int ii=0;ii<32;++ii){ float d=sG[lr][ii]-mu; var += d*d; }
        var *= 0.03125f;
        float rs = rsqrtf(var + 1e-5f);
        const int j0 = wu*2;
        sPred[lr][j0]   = (sG[lr][j0]  -mu)*rs*lngf[j0]   + lnbf[j0];
        sPred[lr][j0+1] = (sG[lr][j0+1]-mu)*rs*lngf[j0+1] + lnbf[j0+1];
      }
      __syncthreads();
      // ---- coalesced out write (block chunk is 2048 contiguous floats) ----
      {
        size_t obase = ((size_t)stepB*NROWS + base)*32;
        #pragma unroll
        for (int it=0; it<2; ++it){
          int idx = tid + it*TPB;
          out[obase + idx] = sPred[idx>>5][idx&31];
        }
      }
    }

    if (stepA >= 0) {
      // ---- h_new = tanh(inp@W1^T + h'@W2^T + b) : wave wu -> j=2wu,2wu+1 ----
      const int j0 = wu*2;
      float a0=b12f[j0], a1=b12f[j0+1];
      if (stepA < 10) {
        #pragma unroll
        for (int ii=0;ii<32;++ii){
          float xv=sX[lr][ii], hv=sHp[lr][ii];
          a0 += xv*W1f[j0*32+ii]     + hv*W2f[j0*32+ii];     // s_load
          a1 += xv*W1f[(j0+1)*32+ii] + hv*W2f[(j0+1)*32+ii];
        }
      } else {
        #pragma unroll
        for (int ii=0;ii<32;++ii){
          float xv=sPred[lr][ii], hv=sHp[lr][ii];
          a0 += xv*W1f[j0*32+ii]     + hv*W2f[j0*32+ii];     // s_load
          a1 += xv*W1f[(j0+1)*32+ii] + hv*W2f[(j0+1)*32+ii];
        }
      }
      {
        float t0 = tanhf(a0), t1 = tanhf(a1);
        sHn[lr][j0]=t0; sHn[lr][j0+1]=t1;       // stays in LDS (no global!)
      }
      __syncthreads();
      // ---- qkv = [h_new, pl] @ W_in^T + b_in : wave wu -> e = wu + 16k ----
      float hn[32];
      #pragma unroll
      for (int f=0;f<32;++f) hn[f]=sHn[lr][f];
      const float pl0 = grb*0.015625f, pl1 = lr*0.015625f;
      #pragma unroll
      for (int k=0;k<7;++k){
        int e = wu + 16*k;                       // wave-uniform
        if (e < 102) {
          float acc = binf[e];
          #pragma unroll
          for (int f=0;f<32;++f) acc += hn[f]*Winf[e*34+f];  // s_load
          acc += pl0*Winf[e*34+32] + pl1*Winf[e*34+33];
          qW[(size_t)e*NROWS + r] = acc;         // coalesced (feature-major)
        }
      }
    }

    // ---- hand-rolled grid barrier (publishes qkv across XCDs) ----
    if (i < 59) {
      __syncthreads();                 // all waves' stores issued+drained
      if (tid == 0) {
        __threadfence();               // release: L2 writeback (agent scope)
        __hip_atomic_fetch_add(&bar[i], 1, __ATOMIC_RELAXED,
                               __HIP_MEMORY_SCOPE_AGENT);
        // bounded poll: escape hatch -> wrong answer instead of dead container
        int polls = 0;
        while (__hip_atomic_load(&bar[i], __ATOMIC_RELAXED,
                                 __HIP_MEMORY_SCOPE_AGENT) < NBLK
               && polls < (1<<21)) {
          __builtin_amdgcn_s_sleep(2);
          ++polls;
        }
        __threadfence();               // acquire: L1/L2 invalidate
      }
      __syncthreads();
    }
  }
}

extern "C" void kernel_launch(void* const* d_in, const int* in_sizes, int n_in,
                              void* d_out, int out_size, void* d_ws, size_t ws_size,
                              hipStream_t stream) {
  const float* x     = (const float*)d_in[0];
  const float* W_x2h = (const float*)d_in[1];
  const float* b_x2h = (const float*)d_in[2];
  const float* W_h2h = (const float*)d_in[3];
  const float* b_h2h = (const float*)d_in[4];
  const float* W_fc2 = (const float*)d_in[5];
  const float* b_fc2 = (const float*)d_in[6];
  const float* ln_g  = (const float*)d_in[7];
  const float* ln_b  = (const float*)d_in[8];
  const float* W_fcsa= (const float*)d_in[9];
  const float* b_fcsa= (const float*)d_in[10];
  const float* W_in  = (const float*)d_in[11];
  const float* b_in  = (const float*)d_in[12];
  const float* W_out = (const float*)d_in[13];
  const float* b_out = (const float*)d_in[14];
  float* ws = (float*)d_ws;
  float* out = (float*)d_out;

  setup_kernel<<<8, 256, 0, stream>>>(W_x2h,b_x2h,W_h2h,b_h2h,W_fc2,b_fc2,ln_g,ln_b,
                                      W_fcsa,b_fcsa,W_in,b_in,W_out,b_out, ws);
  fused_kernel<<<NBLK, TPB, 0, stream>>>(ws, x, out);
}

// Round 4
// 1920.807 us; speedup vs baseline: 1.2314x; 1.2314x over previous
//
#include <hip/hip_runtime.h>

#define NROWS 8192
#define RPB   64
#define TPB   1024     // 16 waves/block, 128 blocks, 1 block/CU (LDS-bound)
#define NBLK  128

// workspace layout (float offsets)
#define OFF_W1   0          // 1024
#define OFF_W2   1024       // 1024
#define OFF_WIN  2048       // 102*34 = 3468
#define OFF_WFC2 5516       // 1024
#define OFF_M    6540       // 32*34 = 1088
#define OFF_B12  7628       // 32
#define OFF_BIN  7660       // 102
#define OFF_B2   7762       // 32
#define OFF_BFC2 7794       // 32
#define OFF_LNG  7826       // 32
#define OFF_LNB  7858       // 32
#define OFF_BAR  7904       // 64 ints (per-step grid-barrier counters)
#define OFF_QKV0 8192
#define QKVN     (NROWS*102)          // feature-major: qkv[e][row]
#define OFF_QKV1 (OFF_QKV0 + QKVN)

__global__ __launch_bounds__(256) void setup_kernel(
    const float* __restrict__ W_x2h, const float* __restrict__ b_x2h,
    const float* __restrict__ W_h2h, const float* __restrict__ b_h2h,
    const float* __restrict__ W_fc2, const float* __restrict__ b_fc2,
    const float* __restrict__ ln_g,  const float* __restrict__ ln_b,
    const float* __restrict__ W_fcsa,const float* __restrict__ b_fcsa,
    const float* __restrict__ W_in,  const float* __restrict__ b_in,
    const float* __restrict__ W_out, const float* __restrict__ b_out,
    float* __restrict__ ws)
{
  int t = blockIdx.x*blockDim.x + threadIdx.x;
  int stride = gridDim.x*blockDim.x;
  for (int i=t;i<1024;i+=stride) ws[OFF_W1+i]   = W_x2h[i];
  for (int i=t;i<1024;i+=stride) ws[OFF_W2+i]   = W_h2h[i];
  for (int i=t;i<3468;i+=stride) ws[OFF_WIN+i]  = W_in[i];
  for (int i=t;i<1024;i+=stride) ws[OFF_WFC2+i] = W_fc2[i];
  for (int i=t;i<32;i+=stride)   ws[OFF_B12+i]  = b_x2h[i] + b_h2h[i];
  for (int i=t;i<102;i+=stride)  ws[OFF_BIN+i]  = b_in[i];
  for (int i=t;i<32;i+=stride)   ws[OFF_BFC2+i] = b_fc2[i];
  for (int i=t;i<32;i+=stride)   ws[OFF_LNG+i]  = ln_g[i];
  for (int i=t;i<32;i+=stride)   ws[OFF_LNB+i]  = ln_b[i];
  // zero grid-barrier counters (re-zeroed every launch/graph replay)
  for (int i=t;i<64;i+=stride)   ((int*)(ws+OFF_BAR))[i] = 0;
  // M = W_fcsa (32x34) @ W_out (34x34)
  for (int idx=t; idx<1088; idx+=stride) {
    int j = idx/34, f = idx - j*34;
    float acc = 0.f;
    for (int e=0;e<34;++e)
      acc += W_fcsa[j*34+e] * W_out[e*34+f];
    ws[OFF_M+idx] = acc;
  }
  for (int j=t;j<32;j+=stride){
    float acc = b_fcsa[j];
    for (int e=0;e<34;++e) acc += W_fcsa[j*34+e] * b_out[e];
    ws[OFF_B2+j] = acc;
  }
}

// Persistent kernel, all 60 steps in one regular launch (128 blocks x 130KB LDS
// -> 1 block/CU, all co-resident on the 256-CU chip by construction).
//
// R3 lesson: agent-scope __threadfence on multi-XCD CDNA4 = full L2
// writeback/invalidate -> every step re-fetched everything (216MB FETCH, 9.5%
// VALUBusy). This version is fence-FREE: the qkv neighbor exchange uses
// RELAXED AGENT-SCOPE atomics (sc0/sc1 bits: write-through past the
// non-coherent per-XCD L2 to the Infinity Cache, loads bypass stale L1/L2).
// Weights / x / out stay L2-resident across all steps. The grid barrier is
// just syncthreads (hipcc drains vmcnt before s_barrier) + relaxed counter.
//
// Block owns one (batch x grid-row) stripe; h_new/h'/pred persist in LDS.
// Its OWN qkv row is written directly into sQKV[own_slot] at compute time, so
// phase 0 only stages the 2 neighbor grid-rows (204 features, coalesced).
__global__ __launch_bounds__(TPB) void fused_kernel(
    float* __restrict__ ws,
    const float* __restrict__ x,
    float* __restrict__ out)
{
  const float* W1f   = ws + OFF_W1;
  const float* W2f   = ws + OFF_W2;
  const float* Winf  = ws + OFF_WIN;
  const float* Wfc2f = ws + OFF_WFC2;
  const float* Mf    = ws + OFF_M;
  const float* b12f  = ws + OFF_B12;
  const float* binf  = ws + OFF_BIN;
  const float* b2f   = ws + OFF_B2;
  const float* bfc2f = ws + OFF_BFC2;
  const float* lngf  = ws + OFF_LNG;
  const float* lnbf  = ws + OFF_LNB;
  int*   bar = (int*)(ws + OFF_BAR);
  float* q0  = ws + OFF_QKV0;
  float* q1  = ws + OFF_QKV1;

  __shared__ float sQKV[3][102][64]; // staged qkv rows (br-1,br,br+1) x feat x gc
  __shared__ float sS[RPB][13];      // 9 scores (stride 13: conflict-free)
  __shared__ float sO[RPB][35];      // attention output (34)
  __shared__ float sHp[RPB][33];     // h' (persistent across steps)
  __shared__ float sG[RPB][33];      // pre-LN fc2 output
  __shared__ float sPred[RPB][33];   // pred (next-step input, persistent)
  __shared__ float sHn[RPB][33];     // h_new (tanh output, persistent)
  __shared__ float sX[RPB][33];      // staged x chunk (steps 0..9)

  const int tid = threadIdx.x;
  const int lr  = tid & 63;
  const int wu  = __builtin_amdgcn_readfirstlane(tid >> 6);  // wave id 0..15
  const int base= blockIdx.x * RPB;
  const int r   = base + lr;
  // block covers exactly one (batch, grid-row); gc == lr
  const int bb  = base >> 12;                    // uniform
  const int grb = (base & 4095) >> 6;            // uniform (unclamped, for pl)
  const int brb = (grb < 1) ? 1 : ((grb > 62) ? 62 : grb);  // uniform clamp
  const int bc  = (lr < 1) ? 1 : ((lr > 62) ? 62 : lr);     // per-lane col clamp
  const int rb0 = (bb << 12) + ((brb - 1) << 6); // global row of stage slot 0
  const int own_slot = grb - brb + 1;            // which slot is OUR grid-row
  const int slotA = (own_slot == 0) ? 1 : 0;     // the two neighbor slots
  const int slotB = (own_slot == 2) ? 1 : 2;

  for (int i = 0; i < 60; ++i) {
    const int stepB = i - 1;
    const int stepA = (i <= 58) ? i : -1;
    float* qR = ((i + 1) & 1) ? q1 : q0;         // qkv of step i-1 (read)
    float* qW = (i & 1) ? q1 : q0;               // qkv of step i (write)

    // ---- phase 0: stage the 2 NEIGHBOR qkv rows into LDS (IF-coherent) ----
    if (stepB >= 0) {
      #pragma unroll
      for (int k = 0; k < 13; ++k) {
        int chunk = wu + 16*k;                   // wave-uniform
        if (chunk < 204) {
          int half = (chunk >= 102);             // wave-uniform
          int e    = chunk - (half ? 102 : 0);   // SGPR
          int slot = half ? slotB : slotA;       // SGPR
          float v = __hip_atomic_load(&qR[(size_t)e*NROWS + rb0 + (slot<<6) + lr],
                                      __ATOMIC_RELAXED, __HIP_MEMORY_SCOPE_AGENT);
          sQKV[slot][e][lr] = v;
        }
      }
    } else {
      // step 0: h' = 0
      sHp[lr][2*wu] = 0.f; sHp[lr][2*wu+1] = 0.f;
    }
    if (stepA >= 0 && stepA < 10) {
      size_t xbase = ((size_t)stepA*NROWS + base)*32;
      #pragma unroll
      for (int it = 0; it < 2; ++it) {
        int idx = tid + it*TPB;
        sX[idx>>5][idx&31] = x[xbase + idx];
      }
    }
    __syncthreads();

    if (stepB >= 0) {
      // ---- phase 1: scores (waves 0..8, m=wu) — pure LDS ----
      if (wu < 9) {
        const int slot = wu / 3;                 // uniform
        const int col  = bc + (wu - slot*3 - 1); // 0..63
        float acc = 0.f;
        #pragma unroll
        for (int e = 0; e < 34; ++e)
          acc += sQKV[1][e][bc] * sQKV[slot][34+e][col];
        sS[lr][wu] = acc * 0.1714985851425088f;  // 1/sqrt(34)
      }
      __syncthreads();
      // ---- phase 2: softmax (redundant per wave) + o slice — pure LDS ----
      {
        float sc[9]; float mx = -1e30f;
        #pragma unroll
        for (int m=0;m<9;++m){ sc[m]=sS[lr][m]; mx=fmaxf(mx,sc[m]); }
        float sum=0.f;
        #pragma unroll
        for (int m=0;m<9;++m){ sc[m]=__expf(sc[m]-mx); sum+=sc[m]; }
        float inv = 1.f/sum;
        float o0=0.f, o1=0.f, o2=0.f;
        const bool e2ok = (wu < 2);              // wave-uniform
        #pragma unroll
        for (int m=0;m<9;++m){
          const int slot = m/3;
          const int col  = bc + (m - slot*3 - 1);
          float wm = sc[m]*inv;
          o0 += wm * sQKV[slot][68+wu][col];
          o1 += wm * sQKV[slot][84+wu][col];
          if (e2ok) o2 += wm * sQKV[slot][100+wu][col];
        }
        sO[lr][wu]    = o0;
        sO[lr][wu+16] = o1;
        if (e2ok) sO[lr][wu+32] = o2;
      }
      __syncthreads();
      // ---- phase 3: h' = h_new(LDS) + o @ M^T + b2 : wave wu -> j=2wu,2wu+1 ----
      {
        const int j0 = wu*2;
        float a0 = b2f[j0], a1 = b2f[j0+1];
        #pragma unroll
        for (int e=0;e<34;++e){
          float ov = sO[lr][e];
          a0 += ov * Mf[j0*34+e];                // s_load weights
          a1 += ov * Mf[(j0+1)*34+e];
        }
        sHp[lr][j0]   = sHn[lr][j0]   + a0;
        sHp[lr][j0+1] = sHn[lr][j0+1] + a1;
      }
      __syncthreads();
      // ---- phase 4: g = h' @ Wfc2^T + b ----
      {
        const int j0 = wu*2;
        float g0 = bfc2f[j0], g1 = bfc2f[j0+1];
        #pragma unroll
        for (int ii=0;ii<32;++ii){
          float hv = sHp[lr][ii];
          g0 += hv * Wfc2f[j0*32+ii];            // s_load
          g1 += hv * Wfc2f[(j0+1)*32+ii];
        }
        sG[lr][j0]=g0; sG[lr][j0+1]=g1;
      }
      __syncthreads();
      // ---- phase 5: layernorm -> sPred ----
      {
        float mu=0.f;
        #pragma unroll
        for (int ii=0;ii<32;++ii) mu += sG[lr][ii];
        mu *= 0.03125f;
        float var=0.f;
        #pragma unroll
        for (int ii=0;ii<32;++ii){ float d=sG[lr][ii]-mu; var += d*d; }
        var *= 0.03125f;
        float rs = rsqrtf(var + 1e-5f);
        const int j0 = wu*2;
        sPred[lr][j0]   = (sG[lr][j0]  -mu)*rs*lngf[j0]   + lnbf[j0];
        sPred[lr][j0+1] = (sG[lr][j0+1]-mu)*rs*lngf[j0+1] + lnbf[j0+1];
      }
      __syncthreads();
      // ---- coalesced out write (block chunk is 2048 contiguous floats) ----
      {
        size_t obase = ((size_t)stepB*NROWS + base)*32;
        #pragma unroll
        for (int it=0; it<2; ++it){
          int idx = tid + it*TPB;
          out[obase + idx] = sPred[idx>>5][idx&31];
        }
      }
    }

    if (stepA >= 0) {
      // ---- h_new = tanh(inp@W1^T + h'@W2^T + b) : wave wu -> j=2wu,2wu+1 ----
      const int j0 = wu*2;
      float a0=b12f[j0], a1=b12f[j0+1];
      if (stepA < 10) {
        #pragma unroll
        for (int ii=0;ii<32;++ii){
          float xv=sX[lr][ii], hv=sHp[lr][ii];
          a0 += xv*W1f[j0*32+ii]     + hv*W2f[j0*32+ii];     // s_load
          a1 += xv*W1f[(j0+1)*32+ii] + hv*W2f[(j0+1)*32+ii];
        }
      } else {
        #pragma unroll
        for (int ii=0;ii<32;++ii){
          float xv=sPred[lr][ii], hv=sHp[lr][ii];
          a0 += xv*W1f[j0*32+ii]     + hv*W2f[j0*32+ii];     // s_load
          a1 += xv*W1f[(j0+1)*32+ii] + hv*W2f[(j0+1)*32+ii];
        }
      }
      {
        float t0 = tanhf(a0), t1 = tanhf(a1);
        sHn[lr][j0]=t0; sHn[lr][j0+1]=t1;       // stays in LDS (no global!)
      }
      __syncthreads();
      // ---- qkv = [h_new, pl] @ W_in^T + b_in : wave wu -> e = wu + 16k ----
      float hn[32];
      #pragma unroll
      for (int f=0;f<32;++f) hn[f]=sHn[lr][f];
      const float pl0 = grb*0.015625f, pl1 = lr*0.015625f;
      #pragma unroll
      for (int k=0;k<7;++k){
        int e = wu + 16*k;                       // wave-uniform
        if (e < 102) {
          float acc = binf[e];
          #pragma unroll
          for (int f=0;f<32;++f) acc += hn[f]*Winf[e*34+f];  // s_load
          acc += pl0*Winf[e*34+32] + pl1*Winf[e*34+33];
          // publish for neighbors: write-through to Infinity Cache (agent
          // coherence point), no fence needed
          __hip_atomic_store(&qW[(size_t)e*NROWS + r], acc,
                             __ATOMIC_RELAXED, __HIP_MEMORY_SCOPE_AGENT);
          // keep our own copy in LDS (next step's own_slot — no re-read)
          sQKV[own_slot][e][lr] = acc;
        }
      }
    }

    // ---- fence-free grid barrier ----
    // __syncthreads drains each wave's vmcnt before s_barrier, so all the
    // block's write-through qkv stores are globally visible at the IF here.
    if (i < 59) {
      __syncthreads();
      if (tid == 0) {
        __hip_atomic_fetch_add(&bar[i], 1, __ATOMIC_RELAXED,
                               __HIP_MEMORY_SCOPE_AGENT);
        int polls = 0;   // bounded poll: wrong answer beats dead container
        while (__hip_atomic_load(&bar[i], __ATOMIC_RELAXED,
                                 __HIP_MEMORY_SCOPE_AGENT) < NBLK
               && polls < (1<<20)) {
          __builtin_amdgcn_s_sleep(1);
          ++polls;
        }
      }
      __syncthreads();
    }
  }
}

extern "C" void kernel_launch(void* const* d_in, const int* in_sizes, int n_in,
                              void* d_out, int out_size, void* d_ws, size_t ws_size,
                              hipStream_t stream) {
  const float* x     = (const float*)d_in[0];
  const float* W_x2h = (const float*)d_in[1];
  const float* b_x2h = (const float*)d_in[2];
  const float* W_h2h = (const float*)d_in[3];
  const float* b_h2h = (const float*)d_in[4];
  const float* W_fc2 = (const float*)d_in[5];
  const float* b_fc2 = (const float*)d_in[6];
  const float* ln_g  = (const float*)d_in[7];
  const float* ln_b  = (const float*)d_in[8];
  const float* W_fcsa= (const float*)d_in[9];
  const float* b_fcsa= (const float*)d_in[10];
  const float* W_in  = (const float*)d_in[11];
  const float* b_in  = (const float*)d_in[12];
  const float* W_out = (const float*)d_in[13];
  const float* b_out = (const float*)d_in[14];
  float* ws = (float*)d_ws;
  float* out = (float*)d_out;

  setup_kernel<<<8, 256, 0, stream>>>(W_x2h,b_x2h,W_h2h,b_h2h,W_fc2,b_fc2,ln_g,ln_b,
                                      W_fcsa,b_fcsa,W_in,b_in,W_out,b_out, ws);
  fused_kernel<<<NBLK, TPB, 0, stream>>>(ws, x, out);
}